// Round 11
// baseline (180.718 us; speedup 1.0000x reference)
//
#include <hip/hip_runtime.h>
#include <math.h>

#define NUM_AGENTS 256
#define HIDDEN 1024
#define RANK 32
#define NTOK 8192
#define TBATCH 16         // tokens per descriptor (two 8-token halves)
#define HB 8              // tokens per half
#define LISTCAP 64        // per-agent token cap (Binomial mean 32, sd 5.7)
#define REGCAP 128        // descriptor slots per XCD region (~66 expected)
#define DSTRIDE 32        // ints per descriptor (128 B)
#define ALPHA_MAX 5.0f
#define LN_EPS 1e-5f

// plain-vector alias: __builtin_nontemporal_* rejects HIP_vector_type
typedef float f32x4 __attribute__((ext_vector_type(4)));

// ---- kernel 0: reset the 8 per-region descriptor counters (graph-safe) ----
__global__ void zero_rc(int* __restrict__ rc) {
    if (threadIdx.x < 8) rc[threadIdx.x] = 0;
}

// ---- kernel 1: scan ids, emit DENSE 128B descriptors of 16 tokens ----------
// Grid 256 (one block per agent). Collect tokens in LDS; reserve contiguous
// slots in region (agent & 7) with ONE atomicAdd; write {agent, nm, tk[0..15]}
// padded by replicating the last token. Same-agent descriptors are adjacent
// -> temporally adjacent on one XCD -> U/V L2 reuse (v7's property).
__global__ __launch_bounds__(256) void scan_kernel(
    const int* __restrict__ ids, int* __restrict__ rc, int* __restrict__ desc)
{
    __shared__ int toklist[LISTCAP];
    __shared__ int cnt, basew;
    const int t = threadIdx.x;
    const int agent = blockIdx.x;
    if (t == 0) { cnt = 0; toklist[0] = 0; }
    __syncthreads();
    #pragma unroll
    for (int it = 0; it < NTOK / 1024; ++it) {          // 8 iters of int4
        int4 v = ((const int4*)ids)[t + 256 * it];
        int ib = 4 * (t + 256 * it);
        if ((v.x & (NUM_AGENTS - 1)) == agent) { int p = atomicAdd(&cnt, 1); if (p < LISTCAP) toklist[p] = ib + 0; }
        if ((v.y & (NUM_AGENTS - 1)) == agent) { int p = atomicAdd(&cnt, 1); if (p < LISTCAP) toklist[p] = ib + 1; }
        if ((v.z & (NUM_AGENTS - 1)) == agent) { int p = atomicAdd(&cnt, 1); if (p < LISTCAP) toklist[p] = ib + 2; }
        if ((v.w & (NUM_AGENTS - 1)) == agent) { int p = atomicAdd(&cnt, 1); if (p < LISTCAP) toklist[p] = ib + 3; }
    }
    __syncthreads();
    const int c = min(cnt, LISTCAP);
    const int ng = (c + TBATCH - 1) / TBATCH;
    if (t == 0 && c > 0)
        basew = atomicAdd(&rc[agent & 7], ng);
    __syncthreads();
    if (t < ng) {
        int slot = basew + t;
        if (slot < REGCAP) {
            int* d = desc + ((size_t)(agent & 7) * REGCAP + slot) * DSTRIDE;
            d[0] = agent;
            d[1] = min(TBATCH, c - t * TBATCH);
            #pragma unroll
            for (int m = 0; m < TBATCH; ++m)
                d[2 + m] = toklist[min(t * TBATCH + m, c - 1)];
        }
    }
}

// ---- kernel 2: one block = one 16-token descriptor; 512 thr = two halves ---
// Grid = 8 regions x REGCAP, region = bid & 7 -> XCD. Half H (threads
// 256H..256H+255) owns tokens m = 8H..8H+7 and runs the v7 body (68-VGPR-
// stable) over th = t & 255: acc[8]/p[8], depth-4 U/V pipelines, red/inter/
// wred aliased into the half's dead Hs row (row 8H; its fragment in h0v).
// Both halves issue identical U/V addresses -> one 256 KB sweep serves 16
// tokens: ~560 sweeps total (v7: 1100) at v7's L2 locality.
//   inter[m] = h[m].U[a];  pert[m] = inter[m].V[a];
//   out[m] = LayerNorm(h[m] + alpha*pert[m]) * gamma + beta
__global__ __launch_bounds__(512) void div_inject_kernel(
    const float* __restrict__ hglob,
    const float* __restrict__ log_alpha,
    const float* __restrict__ gamma,
    const float* __restrict__ beta,
    const float* __restrict__ U,
    const float* __restrict__ V,
    const int* __restrict__ rc,
    const int* __restrict__ desc,
    float* __restrict__ out)
{
    __shared__ __align__(16) float Hs[TBATCH][HIDDEN];   // 65536 B — everything
    // Per-half alias inside the half's dead row Hs[8H][0..1023]:
    //   red0h[w*256 + m*32 + r] : phase-2 per-wave partials (w = wave-in-half)
    //   interh[m*32 + r]        : merged intermediate (red0h[0..255])
    //   wredh[w*16 + {0|8} + m] : LN partials (red0h[256..319]; disjoint from
    //                             interh reads, so no extra barrier needed)

    const int t = threadIdx.x;
    const int region = blockIdx.x & 7;
    const int slot = blockIdx.x >> 3;

    const int rcnt = min(rc[region], REGCAP);
    if (slot >= rcnt) return;

    const int* dsc = desc + ((size_t)region * REGCAP + slot) * DSTRIDE;
    const int a  = dsc[0];
    const int nm = dsc[1];

    const int th = t & 255;             // thread-in-half
    const int mbase = (t >> 8) * HB;    // 0 or 8 (uniform per wave)
    const int nmh = min(max(nm - mbase, 0), HB);   // tokens this half writes

    float* red0h = &Hs[mbase][0];
    float* interh = red0h;
    float* wredh = red0h + 256;

    const float* Ua = U + (size_t)a * (HIDDEN * RANK);
    const float* Va = V + (size_t)a * (RANK * HIDDEN);

    const int r4 = (th & 7) * 4;   // rank quad: 0,4,...,28
    const int ks = th >> 3;        // k-slice 0..31
    const int c  = th * 4;         // this thread's 4 columns (within the half)
    const int wave = th >> 6, lane = t & 63;

    // ---- issue U batch 0 immediately ----
    float4 ub[2][4];
    #pragma unroll
    for (int j = 0; j < 4; ++j)
        ub[0][j] = *(const float4*)(Ua + (ks + 32 * j) * RANK + r4);

    // ---- token indices: uniform descriptor reads -> SGPRs ----
    int tk[HB];
    #pragma unroll
    for (int m = 0; m < HB; ++m)
        tk[m] = __builtin_amdgcn_readfirstlane(dsc[2 + mbase + m]);

    const float alpha = fminf(__expf(log_alpha[0]), ALPHA_MAX);

    // ---- stage this half's 8 h rows; keep row-0 fragment in regs ----
    f32x4 h0v;
    {
        f32x4 hv[HB];
        #pragma unroll
        for (int m = 0; m < HB; ++m)
            hv[m] = __builtin_nontemporal_load((const f32x4*)(hglob + (size_t)tk[m] * HIDDEN + c));
        h0v = hv[0];
        #pragma unroll
        for (int m = 0; m < HB; ++m)
            *(f32x4*)(&Hs[mbase + m][c]) = hv[m];
    }
    __syncthreads();                       // [A] Hs ready

    // ---- phase 2: inter[m][r] = sum_hh Hs[m][hh] * U[hh][r] ----
    // depth-4 double-buffered U pipeline (v7 formulation)
    float4 acc[HB];
    #pragma unroll
    for (int m = 0; m < HB; ++m) acc[m] = make_float4(0.f, 0.f, 0.f, 0.f);
    #pragma unroll
    for (int jb = 0; jb < 8; ++jb) {
        const int cur = jb & 1;
        if (jb < 7) {
            #pragma unroll
            for (int j = 0; j < 4; ++j)
                ub[cur ^ 1][j] = *(const float4*)(Ua + (ks + 32 * (4 * (jb + 1) + j)) * RANK + r4);
        }
        #pragma unroll
        for (int j = 0; j < 4; ++j) {
            const int hh = ks + 32 * (4 * jb + j);
            float4 u = ub[cur][j];
            #pragma unroll
            for (int m = 0; m < HB; ++m) {
                float h0 = Hs[mbase + m][hh];
                acc[m].x += h0 * u.x;
                acc[m].y += h0 * u.y;
                acc[m].z += h0 * u.z;
                acc[m].w += h0 * u.w;
            }
        }
    }
    // reduce over the 8 k-slices within each wave (lane bits 3..5)
    #pragma unroll
    for (int off = 8; off <= 32; off <<= 1) {
        #pragma unroll
        for (int m = 0; m < HB; ++m) {
            acc[m].x += __shfl_xor(acc[m].x, off, 64);
            acc[m].y += __shfl_xor(acc[m].y, off, 64);
            acc[m].z += __shfl_xor(acc[m].z, off, 64);
            acc[m].w += __shfl_xor(acc[m].w, off, 64);
        }
    }
    __syncthreads();                       // [B] Hs row reads done -> dead rows reusable
    if (lane < 8) {
        #pragma unroll
        for (int m = 0; m < HB; ++m)
            *(float4*)(&red0h[wave * 256 + m * 32 + r4]) = acc[m];
    }

    // prefetch V batch 0 before the merge barrier
    float4 vb[2][4];
    #pragma unroll
    for (int j = 0; j < 4; ++j)
        vb[0][j] = *(const float4*)(Va + j * HIDDEN + c);

    __syncthreads();                       // [C] red written
    interh[th] = red0h[th] + red0h[256 + th] + red0h[512 + th] + red0h[768 + th];
    __syncthreads();                       // [D] inter ready

    // ---- phase 3: p[m][c..c+3] = sum_r inter[m][r] * V[r][c..c+3] ----
    float4 p[HB];
    #pragma unroll
    for (int m = 0; m < HB; ++m) p[m] = make_float4(0.f, 0.f, 0.f, 0.f);
    #pragma unroll
    for (int rb = 0; rb < 8; ++rb) {
        const int cur = rb & 1;
        if (rb < 7) {
            #pragma unroll
            for (int j = 0; j < 4; ++j)
                vb[cur ^ 1][j] = *(const float4*)(Va + (4 * (rb + 1) + j) * HIDDEN + c);
        }
        #pragma unroll
        for (int j = 0; j < 4; ++j) {
            const int r = 4 * rb + j;
            float4 v = vb[cur][j];
            #pragma unroll
            for (int m = 0; m < HB; ++m) {
                float ir = interh[m * 32 + r];   // uniform LDS broadcast
                p[m].x += ir * v.x;
                p[m].y += ir * v.y;
                p[m].z += ir * v.z;
                p[m].w += ir * v.w;
            }
        }
    }

    // ---- d = h + alpha*p IN PLACE; LayerNorm stats (m=0 h from regs) ----
    float sred[HB], q[HB];
    #pragma unroll
    for (int m = 0; m < HB; ++m) {
        f32x4 h4 = (m == 0) ? h0v : *(const f32x4*)(&Hs[mbase + m][c]);
        p[m].x = h4.x + alpha * p[m].x;
        p[m].y = h4.y + alpha * p[m].y;
        p[m].z = h4.z + alpha * p[m].z;
        p[m].w = h4.w + alpha * p[m].w;
        sred[m] = p[m].x + p[m].y + p[m].z + p[m].w;
        q[m] = p[m].x * p[m].x + p[m].y * p[m].y + p[m].z * p[m].z + p[m].w * p[m].w;
    }
    #pragma unroll
    for (int off = 32; off > 0; off >>= 1) {
        #pragma unroll
        for (int m = 0; m < HB; ++m) {
            sred[m] += __shfl_xor(sred[m], off, 64);
            q[m] += __shfl_xor(q[m], off, 64);
        }
    }
    if (lane == 0) {
        #pragma unroll
        for (int m = 0; m < HB; ++m) {     // static indices only
            wredh[wave * 16 + m] = sred[m];
            wredh[wave * 16 + 8 + m] = q[m];
        }
    }
    __syncthreads();                       // [E] stats partials ready

    // stats computed redundantly by every thread (LDS broadcasts)
    const float4 gv = *(const float4*)(gamma + c);
    const float4 bv = *(const float4*)(beta + c);
    #pragma unroll
    for (int m = 0; m < HB; ++m) {
        if (m < nmh) {                       // wave-uniform guard
            float S = wredh[m] + wredh[16 + m] + wredh[32 + m] + wredh[48 + m];
            float Q = wredh[8 + m] + wredh[24 + m] + wredh[40 + m] + wredh[56 + m];
            float mean = S * (1.0f / HIDDEN);
            float rstd = rsqrtf(Q * (1.0f / HIDDEN) - mean * mean + LN_EPS);
            f32x4 o;
            o.x = (p[m].x - mean) * rstd * gv.x + bv.x;
            o.y = (p[m].y - mean) * rstd * gv.y + bv.y;
            o.z = (p[m].z - mean) * rstd * gv.z + bv.z;
            o.w = (p[m].w - mean) * rstd * gv.w + bv.w;
            __builtin_nontemporal_store(o, (f32x4*)(out + (size_t)tk[m] * HIDDEN + c));
        }
    }
}

extern "C" void kernel_launch(void* const* d_in, const int* in_sizes, int n_in,
                              void* d_out, int out_size, void* d_ws, size_t ws_size,
                              hipStream_t stream) {
    const float* h     = (const float*)d_in[0];
    const float* la    = (const float*)d_in[1];
    const float* gamma = (const float*)d_in[2];
    const float* beta  = (const float*)d_in[3];
    const float* U     = (const float*)d_in[4];
    const float* V     = (const float*)d_in[5];
    const int* ids     = (const int*)d_in[6];
    float* out         = (float*)d_out;

    int* rc   = (int*)d_ws;                 // 8 counters (64 B reserved)
    int* desc = rc + 16;                    // 8 x 128 x 32 ints = 128 KB

    zero_rc<<<1, 64, 0, stream>>>(rc);
    scan_kernel<<<NUM_AGENTS, 256, 0, stream>>>(ids, rc, desc);
    div_inject_kernel<<<8 * REGCAP, 512, 0, stream>>>(
        h, la, gamma, beta, U, V, rc, desc, out);
}

// Round 12
// 165.358 us; speedup vs baseline: 1.0929x; 1.0929x over previous
//
#include <hip/hip_runtime.h>
#include <math.h>

#define NUM_AGENTS 256
#define HIDDEN 1024
#define RANK 32
#define NTOK 8192
#define TBATCH 8          // tokens per compute block
#define MAXPER 128        // per-agent token cap (Binomial mean 32; 128 = +17 sigma)
#define REGCAP 256        // descriptor slots per XCD region
#define PREF 256          // prefetch blocks at the head of the compute grid
#define ALPHA_MAX 5.0f
#define LN_EPS 1e-5f

// plain-vector alias: __builtin_nontemporal_* rejects HIP_vector_type
typedef float f32x4 __attribute__((ext_vector_type(4)));

// ---- kernel 0: reset the 8 per-region descriptor counters (graph-safe) ----
__global__ void zero_rc(int* __restrict__ rc) {
    if (threadIdx.x < 8) rc[threadIdx.x] = 0;
}

// ---- kernel 1: scan ids, emit DENSE 64B group descriptors ------------------
// Grid 256 (one block per agent). Collect the agent's tokens in LDS, then
// reserve contiguous slots in region (agent & 7) via ONE global atomic and
// write descriptors {agent, nm, tk[0..7]} (padded by replication). Same-agent
// groups land in one region -> one XCD -> U/V L2 reuse; regions balanced.
__global__ __launch_bounds__(256) void scan_kernel(
    const int* __restrict__ ids, int* __restrict__ rc, int* __restrict__ desc)
{
    __shared__ int toklist[MAXPER];
    __shared__ int cnt, basew;
    const int t = threadIdx.x;
    const int agent = blockIdx.x;
    if (t == 0) cnt = 0;
    __syncthreads();
    #pragma unroll
    for (int it = 0; it < NTOK / 1024; ++it) {          // 8 iters of int4
        int4 v = ((const int4*)ids)[t + 256 * it];
        int ib = 4 * (t + 256 * it);
        if ((v.x & (NUM_AGENTS - 1)) == agent) { int p = atomicAdd(&cnt, 1); if (p < MAXPER) toklist[p] = ib + 0; }
        if ((v.y & (NUM_AGENTS - 1)) == agent) { int p = atomicAdd(&cnt, 1); if (p < MAXPER) toklist[p] = ib + 1; }
        if ((v.z & (NUM_AGENTS - 1)) == agent) { int p = atomicAdd(&cnt, 1); if (p < MAXPER) toklist[p] = ib + 2; }
        if ((v.w & (NUM_AGENTS - 1)) == agent) { int p = atomicAdd(&cnt, 1); if (p < MAXPER) toklist[p] = ib + 3; }
    }
    __syncthreads();
    const int c = min(cnt, MAXPER);
    const int ng = (c + TBATCH - 1) / TBATCH;
    if (t == 0 && c > 0)
        basew = atomicAdd(&rc[agent & 7], ng);
    __syncthreads();
    if (t < ng) {
        int slot = basew + t;
        if (slot < REGCAP) {
            int* d = desc + ((size_t)(agent & 7) * REGCAP + slot) * 16;
            d[0] = agent;
            d[1] = min(TBATCH, c - t * TBATCH);
            #pragma unroll
            for (int m = 0; m < TBATCH; ++m)
                d[2 + m] = toklist[min(t * TBATCH + m, c - 1)];
        }
    }
}

// ---- kernel 2: prefetch head + one block = one descriptor ------------------
// bid < PREF: stream a 256 KB chunk of U+V with cache-allocating loads (warms
//   the 256 MB L3 at full TLP while early compute blocks run) and exit.
//   Rationale: v7's profile shows the tail is the per-agent COLD first sweep
//   (256 KB from HBM at depth-4 outstanding ~ 900 cyc/step ~ 26 us); once
//   U/V is L3-resident the sweeps are ~500-cyc hits with high bank BW.
// bid >= PREF: EXACT v7 body (68-VGPR-stable, best measured: 52 us).
//   Grid (after head) = 8 regions x REGCAP, region = rbid & 7 -> XCD;
//   same-agent descriptors adjacent -> U/V L2/L3 reuse.
//   inter[m] = h[m].U[a];  pert[m] = inter[m].V[a];
//   out[m] = LayerNorm(h[m] + alpha*pert[m]) * gamma + beta
// LDS = exactly 32768 B (red/inter/wred aliased onto Hs[0]; row-0 fragment
// kept in h0v regs; transitions barrier-separated).
__global__ __launch_bounds__(512) void div_inject_kernel(
    const float* __restrict__ hglob,
    const float* __restrict__ log_alpha,
    const float* __restrict__ gamma,
    const float* __restrict__ beta,
    const float* __restrict__ U,
    const float* __restrict__ V,
    const int* __restrict__ rc,
    const int* __restrict__ desc,
    float* __restrict__ out)
{
    __shared__ __align__(16) float Hs[TBATCH][HIDDEN];   // 32768 B — everything
    float* red0  = &Hs[0][0];
    float* inter = red0;
    float* wred  = red0 + 256;

    const int t = threadIdx.x;

    // ---- prefetch head: warm L3 with U/V (plain loads allocate in MALL) ----
    if (blockIdx.x < PREF) {
        const size_t base = (size_t)blockIdx.x * 32768;   // 128 KB of U + 128 KB of V
        float s = 0.f;
        #pragma unroll 4
        for (int i = t; i < 8192; i += 256) {
            f32x4 u = *(const f32x4*)(U + base + 4 * (size_t)i);
            f32x4 v = *(const f32x4*)(V + base + 4 * (size_t)i);
            s += u.x + v.x;
        }
        asm volatile("" :: "v"(s));     // keep loads alive (no DCE)
        return;
    }

    const int rbid = blockIdx.x - PREF;
    const int region = rbid & 7;
    const int slot = rbid >> 3;

    const int rcnt = min(rc[region], REGCAP);
    if (slot >= rcnt) return;

    const int* dsc = desc + ((size_t)region * REGCAP + slot) * 16;
    const int a  = dsc[0];
    const int nm = dsc[1];
    int tk[TBATCH];
    #pragma unroll
    for (int m = 0; m < TBATCH; ++m) tk[m] = dsc[2 + m];

    const float* Ua = U + (size_t)a * (HIDDEN * RANK);
    const float* Va = V + (size_t)a * (RANK * HIDDEN);

    const int r4 = (t & 7) * 4;   // rank quad: 0,4,...,28
    const int ks = t >> 3;        // k-slice 0..31
    const int c  = t * 4;         // this thread's 4 output columns
    const int wave = t >> 6, lane = t & 63;

    // ---- issue U batch 0 immediately ----
    float4 ub[2][4];
    #pragma unroll
    for (int j = 0; j < 4; ++j)
        ub[0][j] = *(const float4*)(Ua + (ks + 32 * j) * RANK + r4);

    const float alpha = fminf(__expf(log_alpha[0]), ALPHA_MAX);

    // ---- stage h rows; keep row-0 fragment in regs (Hs[0] reused as red) ----
    f32x4 h0v;
    {
        f32x4 hv[TBATCH];
        #pragma unroll
        for (int m = 0; m < TBATCH; ++m)
            hv[m] = __builtin_nontemporal_load((const f32x4*)(hglob + (size_t)tk[m] * HIDDEN + c));
        h0v = hv[0];
        #pragma unroll
        for (int m = 0; m < TBATCH; ++m)
            *(f32x4*)(&Hs[m][c]) = hv[m];
    }
    __syncthreads();                       // [A] Hs ready

    // ---- phase 2: inter[m][r] = sum_hh Hs[m][hh] * U[hh][r] ----
    // depth-4 double-buffered U pipeline
    float4 acc[TBATCH];
    #pragma unroll
    for (int m = 0; m < TBATCH; ++m) acc[m] = make_float4(0.f, 0.f, 0.f, 0.f);
    #pragma unroll
    for (int jb = 0; jb < 8; ++jb) {
        const int cur = jb & 1;
        if (jb < 7) {
            #pragma unroll
            for (int j = 0; j < 4; ++j)
                ub[cur ^ 1][j] = *(const float4*)(Ua + (ks + 32 * (4 * (jb + 1) + j)) * RANK + r4);
        }
        #pragma unroll
        for (int j = 0; j < 4; ++j) {
            const int hh = ks + 32 * (4 * jb + j);
            float4 u = ub[cur][j];
            #pragma unroll
            for (int m = 0; m < TBATCH; ++m) {
                float h0 = Hs[m][hh];
                acc[m].x += h0 * u.x;
                acc[m].y += h0 * u.y;
                acc[m].z += h0 * u.z;
                acc[m].w += h0 * u.w;
            }
        }
    }
    // reduce over the 8 k-slices within each wave (lane bits 3..5)
    #pragma unroll
    for (int off = 8; off <= 32; off <<= 1) {
        #pragma unroll
        for (int m = 0; m < TBATCH; ++m) {
            acc[m].x += __shfl_xor(acc[m].x, off, 64);
            acc[m].y += __shfl_xor(acc[m].y, off, 64);
            acc[m].z += __shfl_xor(acc[m].z, off, 64);
            acc[m].w += __shfl_xor(acc[m].w, off, 64);
        }
    }
    __syncthreads();                       // [B] all Hs[0] reads done -> reusable
    if (lane < 8) {
        #pragma unroll
        for (int m = 0; m < TBATCH; ++m)
            *(float4*)(&red0[wave * 256 + m * 32 + r4]) = acc[m];
    }

    // prefetch V batch 0 before the merge barrier
    float4 vb[2][4];
    #pragma unroll
    for (int j = 0; j < 4; ++j)
        vb[0][j] = *(const float4*)(Va + j * HIDDEN + c);

    __syncthreads();                       // [C] red written
    {
        int m = t >> 5, rr = t & 31;       // thread-exclusive RMW merge
        inter[m * 32 + rr] = red0[m * 32 + rr] + red0[256 + m * 32 + rr]
                           + red0[512 + m * 32 + rr] + red0[768 + m * 32 + rr];
    }
    __syncthreads();                       // [D] inter ready

    // ---- phase 3: p[m][c..c+3] = sum_r inter[m][r] * V[r][c..c+3] ----
    float4 p[TBATCH];
    #pragma unroll
    for (int m = 0; m < TBATCH; ++m) p[m] = make_float4(0.f, 0.f, 0.f, 0.f);
    #pragma unroll
    for (int rb = 0; rb < 8; ++rb) {
        const int cur = rb & 1;
        if (rb < 7) {
            #pragma unroll
            for (int j = 0; j < 4; ++j)
                vb[cur ^ 1][j] = *(const float4*)(Va + (4 * (rb + 1) + j) * HIDDEN + c);
        }
        #pragma unroll
        for (int j = 0; j < 4; ++j) {
            const int r = 4 * rb + j;
            float4 v = vb[cur][j];
            #pragma unroll
            for (int m = 0; m < TBATCH; ++m) {
                float ir = inter[m * 32 + r];   // uniform LDS broadcast
                p[m].x += ir * v.x;
                p[m].y += ir * v.y;
                p[m].z += ir * v.z;
                p[m].w += ir * v.w;
            }
        }
    }

    // ---- d = h + alpha*p IN PLACE; LayerNorm stats (m=0 h from regs) ----
    float s[TBATCH], q[TBATCH];
    #pragma unroll
    for (int m = 0; m < TBATCH; ++m) {
        f32x4 h4 = (m == 0) ? h0v : *(const f32x4*)(&Hs[m][c]);
        p[m].x = h4.x + alpha * p[m].x;
        p[m].y = h4.y + alpha * p[m].y;
        p[m].z = h4.z + alpha * p[m].z;
        p[m].w = h4.w + alpha * p[m].w;
        s[m] = p[m].x + p[m].y + p[m].z + p[m].w;
        q[m] = p[m].x * p[m].x + p[m].y * p[m].y + p[m].z * p[m].z + p[m].w * p[m].w;
    }
    #pragma unroll
    for (int off = 32; off > 0; off >>= 1) {
        #pragma unroll
        for (int m = 0; m < TBATCH; ++m) {
            s[m] += __shfl_xor(s[m], off, 64);
            q[m] += __shfl_xor(q[m], off, 64);
        }
    }
    if (lane == 0) {
        #pragma unroll
        for (int m = 0; m < TBATCH; ++m) {     // static indices only
            wred[wave * 16 + m] = s[m];
            wred[wave * 16 + 8 + m] = q[m];
        }
    }
    __syncthreads();                       // [E] stats partials ready

    // stats computed redundantly by every thread (LDS broadcasts)
    const float4 gv = *(const float4*)(gamma + c);
    const float4 bv = *(const float4*)(beta + c);
    #pragma unroll
    for (int m = 0; m < TBATCH; ++m) {
        if (m < nm) {                        // nm block-uniform
            float S = wred[m] + wred[16 + m] + wred[32 + m] + wred[48 + m];
            float Q = wred[8 + m] + wred[24 + m] + wred[40 + m] + wred[56 + m];
            float mean = S * (1.0f / HIDDEN);
            float rstd = rsqrtf(Q * (1.0f / HIDDEN) - mean * mean + LN_EPS);
            f32x4 o;
            o.x = (p[m].x - mean) * rstd * gv.x + bv.x;
            o.y = (p[m].y - mean) * rstd * gv.y + bv.y;
            o.z = (p[m].z - mean) * rstd * gv.z + bv.z;
            o.w = (p[m].w - mean) * rstd * gv.w + bv.w;
            __builtin_nontemporal_store(o, (f32x4*)(out + (size_t)tk[m] * HIDDEN + c));
        }
    }
}

extern "C" void kernel_launch(void* const* d_in, const int* in_sizes, int n_in,
                              void* d_out, int out_size, void* d_ws, size_t ws_size,
                              hipStream_t stream) {
    const float* h     = (const float*)d_in[0];
    const float* la    = (const float*)d_in[1];
    const float* gamma = (const float*)d_in[2];
    const float* beta  = (const float*)d_in[3];
    const float* U     = (const float*)d_in[4];
    const float* V     = (const float*)d_in[5];
    const int* ids     = (const int*)d_in[6];
    float* out         = (float*)d_out;

    int* rc   = (int*)d_ws;                 // 8 counters (64 B reserved)
    int* desc = rc + 16;                    // 8 regions x REGCAP x 16 ints = 128 KB

    zero_rc<<<1, 64, 0, stream>>>(rc);
    scan_kernel<<<NUM_AGENTS, 256, 0, stream>>>(ids, rc, desc);
    div_inject_kernel<<<PREF + 8 * REGCAP, 256, 0, stream>>>(
        h, la, gamma, beta, U, V, rc, desc, out);
}